// Round 7
// baseline (57.240 us; speedup 1.0000x reference)
//
#include <hip/hip_runtime.h>

typedef float v2f __attribute__((ext_vector_type(2)));

namespace {
constexpr int kB = 16384;
constexpr int kC = 1000;
constexpr int kNElem = kB * kC;           // 16,384,000
constexpr int kNV8 = kNElem / 8;          // 2,048,000 (8-float chunks)
constexpr int kBlocks = 1280;             // <=7 iters -> <=56 elems/thread (6-bit fields safe)
constexpr int kThreads = 256;
constexpr int kStride = kBlocks * kThreads;  // 327,680
constexpr double kScale = 1048576.0;      // 2^20 fixed point for u64 sum atomics
}

// ws: wsll[0..9] = u64 fixed-point hinge sums acc_j = sum max(bce, c_j) (c_0=0 -> T)
//     wsu[0..9]  = u32 per-bin counts N_k
// finalize (f64): cnt_j = sum_{k>=j} N_k; cum_j = acc_j - c_j*(N - cnt_j);
//                 S_k = cum_k - cum_{k+1}; loss = (1/n) sum_{N_k>0} S_k/N_k.

__device__ __forceinline__ void ghmc_elem(float L, float& bce, unsigned& bin)
{
    const float kLn2   = 0.6931471805599453f;
    const float kNRLn2 = -1.4426950408889634f;
    const float en  = __builtin_amdgcn_exp2f(kNRLn2 * fabsf(L));  // e^{-|L|}
    const float den = 1.f + en;
    const float lg  = __builtin_amdgcn_logf(den);                 // log2(den)
    const float r   = __builtin_amdgcn_rcpf(den);
    bce = fmaf(lg, kLn2, fmaxf(L, 0.f));                          // softplus(L)
    unsigned babs = (unsigned)(10.f * r);
    babs = babs > 9u ? 9u : babs;                                 // in [5,9]
    bin = (L >= 0.f) ? babs : 9u - babs;
}

__device__ __forceinline__ void proc4(const float4 v,
    v2f& a01, v2f& a23, v2f& a45, v2f& a67, v2f& a89,
    unsigned long long& hcnt,
    const v2f C01, const v2f C23, const v2f C45, const v2f C67, const v2f C89)
{
    const float lv[4] = {v.x, v.y, v.z, v.w};
    #pragma unroll
    for (int e = 0; e < 4; ++e) {
        float bce; unsigned bin;
        ghmc_elem(lv[e], bce, bin);
        hcnt += 1ull << (6u * bin);
        const v2f b2 = {bce, bce};
        a01 += __builtin_elementwise_max(b2, C01);
        a23 += __builtin_elementwise_max(b2, C23);
        a45 += __builtin_elementwise_max(b2, C45);
        a67 += __builtin_elementwise_max(b2, C67);
        a89 += __builtin_elementwise_max(b2, C89);
    }
}

__global__ __launch_bounds__(kThreads) void ghmc_main(
    const float* __restrict__ logits,
    unsigned long long* __restrict__ wsll,
    unsigned* __restrict__ wsu)
{
    const v2f C01 = {0.0f,        0.10536052f};
    const v2f C23 = {0.22314355f, 0.35667494f};
    const v2f C45 = {0.51082562f, 0.69314718f};
    const v2f C67 = {0.91629073f, 1.20397280f};
    const v2f C89 = {1.60943791f, 2.30258509f};

    v2f a01 = {0.f,0.f}, a23 = {0.f,0.f}, a45 = {0.f,0.f},
        a67 = {0.f,0.f}, a89 = {0.f,0.f};
    unsigned long long hcnt = 0ull;

    const int gid = blockIdx.x * blockDim.x + threadIdx.x;
    const int n = (kNV8 - 1 - gid) / kStride + 1;   // 6 or 7 iterations
    const float4* __restrict__ Lp = reinterpret_cast<const float4*>(logits);

    // depth-2 software pipeline, clamped prefetch addresses (over-load harmless)
    int i = gid;
    int ib = i + kStride;     if (ib >= kNV8) ib = kNV8 - 1;
    float4 a0 = Lp[2 * i],  a1 = Lp[2 * i + 1];
    float4 b0 = Lp[2 * ib], b1 = Lp[2 * ib + 1];

    for (int k = 0; k < n; ++k) {
        int ic = i + 2 * kStride; if (ic >= kNV8) ic = kNV8 - 1;
        const float4 c0 = Lp[2 * ic], c1 = Lp[2 * ic + 1];
        proc4(a0, a01, a23, a45, a67, a89, hcnt, C01, C23, C45, C67, C89);
        proc4(a1, a01, a23, a45, a67, a89, hcnt, C01, C23, C45, C67, C89);
        a0 = b0; a1 = b1; b0 = c0; b1 = c1;
        i += kStride;
    }

    // expand 6-bit fields -> two u64 with 12-bit fields (wave sum <= 56*64 = 3584 < 4096)
    unsigned long long lo = 0ull, hi = 0ull;
    #pragma unroll
    for (int k = 0; k < 5; ++k) {
        lo += ((hcnt >> (6 * k))       & 63ull) << (12 * k);
        hi += ((hcnt >> (6 * (k + 5))) & 63ull) << (12 * k);
    }
    float r10[10] = {a01.x, a01.y, a23.x, a23.y, a45.x, a45.y, a67.x, a67.y, a89.x, a89.y};
    #pragma unroll
    for (int off = 32; off > 0; off >>= 1) {
        #pragma unroll
        for (int k = 0; k < 10; ++k) r10[k] += __shfl_down(r10[k], off);
        lo += __shfl_down(lo, off);
        hi += __shfl_down(hi, off);
    }

    __shared__ float              sf[4][10];
    __shared__ unsigned long long sc[4][2];
    const int wave = threadIdx.x >> 6;
    const int lane = threadIdx.x & 63;
    if (lane == 0) {
        #pragma unroll
        for (int k = 0; k < 10; ++k) sf[wave][k] = r10[k];
        sc[wave][0] = lo; sc[wave][1] = hi;
    }
    __syncthreads();
    const int t = threadIdx.x;
    if (t < 10) {
        const float s = sf[0][t] + sf[1][t] + sf[2][t] + sf[3][t];
        atomicAdd(&wsll[t], (unsigned long long)(long long)((double)s * kScale));
    } else if (t < 20) {
        const int b = t - 10;
        const int half = (b < 5) ? 0 : 1;
        const int sh = 12 * (b < 5 ? b : b - 5);
        unsigned s = 0;
        #pragma unroll
        for (int w = 0; w < 4; ++w) s += (unsigned)((sc[w][half] >> sh) & 4095ull);
        atomicAdd(&wsu[b], s);
    }
}

// Per-row target correction: subtract the non-target contribution the main
// kernel added for the target element, add the true target contribution.
__global__ __launch_bounds__(256) void ghmc_fix(
    const float* __restrict__ logits,
    const int* __restrict__ tgt,
    unsigned long long* __restrict__ wsll,
    unsigned* __restrict__ wsu)
{
    const float cjf[10] = {0.0f,
        0.10536052f, 0.22314355f, 0.35667494f, 0.51082562f, 0.69314718f,
        0.91629073f, 1.20397280f, 1.60943791f, 2.30258509f};

    const int r = blockIdx.x * 256 + threadIdx.x;   // 64 blocks x 256 = 16384 = kB
    const int t = tgt[r];
    const float L = logits[r * kC + t];

    float bn_; unsigned bn;
    ghmc_elem(L, bn_, bn);                 // bitwise-identical to main's per-elem math
    const float bt_ = bn_ - L;             // softplus(-L) = softplus(L) - L
    float btd; unsigned bt;
    ghmc_elem(-L, btd, bt);                // reuse for the bin only
    (void)btd;

    float d[10];
    #pragma unroll
    for (int j = 0; j < 10; ++j) d[j] = fmaxf(bt_, cjf[j]) - fmaxf(bn_, cjf[j]);

    #pragma unroll
    for (int off = 32; off > 0; off >>= 1)
        #pragma unroll
        for (int j = 0; j < 10; ++j) d[j] += __shfl_down(d[j], off);

    int cd[10];
    #pragma unroll
    for (int k = 0; k < 10; ++k)
        cd[k] = (int)__popcll(__ballot(bt == (unsigned)k)) -
                (int)__popcll(__ballot(bn == (unsigned)k));

    __shared__ float sfx[4][10];
    __shared__ int   scx[4][10];
    const int wave = threadIdx.x >> 6;
    const int lane = threadIdx.x & 63;
    if (lane == 0) {
        #pragma unroll
        for (int j = 0; j < 10; ++j) { sfx[wave][j] = d[j]; scx[wave][j] = cd[j]; }
    }
    __syncthreads();
    const int tx = threadIdx.x;
    if (tx < 10) {
        const float s = sfx[0][tx] + sfx[1][tx] + sfx[2][tx] + sfx[3][tx];
        atomicAdd(&wsll[tx], (unsigned long long)(long long)((double)s * kScale));
    } else if (tx < 20) {
        const int b = tx - 10;
        const int s = scx[0][b] + scx[1][b] + scx[2][b] + scx[3][b];
        atomicAdd(&wsu[b], (unsigned)s);   // two's-complement wrap is exact
    }
}

__global__ void ghmc_final(const unsigned long long* __restrict__ wsll,
                           const unsigned* __restrict__ wsu,
                           float* __restrict__ out)
{
    if (threadIdx.x == 0 && blockIdx.x == 0) {
        const double cj[10] = {0.0,
            0.10536051565782630, 0.22314355131420976, 0.35667494393873245,
            0.51082562376599072, 0.69314718055994531, 0.91629073187415511,
            1.20397280432593600, 1.60943791243410040, 2.30258509299404570};
        double N[10], cnt[11], cum[11];
        for (int k = 0; k < 10; ++k) N[k] = (double)wsu[k];
        cnt[10] = 0.0;
        for (int j = 9; j >= 0; --j) cnt[j] = cnt[j + 1] + N[j];
        cum[10] = 0.0;
        cum[0] = (double)(long long)wsll[0] / kScale;            // T (c=0 exact)
        for (int j = 1; j <= 9; ++j) {
            const double acc = (double)(long long)wsll[j] / kScale;
            cum[j] = acc - cj[j] * ((double)kNElem - cnt[j]);
        }
        double loss = 0.0, n = 0.0;
        for (int k = 0; k < 10; ++k) {
            if (N[k] > 0.0) { n += 1.0; loss += (cum[k] - cum[k + 1]) / N[k]; }
        }
        out[0] = (float)(loss / (n > 1.0 ? n : 1.0));
    }
}

extern "C" void kernel_launch(void* const* d_in, const int* in_sizes, int n_in,
                              void* d_out, int out_size, void* d_ws, size_t ws_size,
                              hipStream_t stream)
{
    const float* logits = (const float*)d_in[0];
    const int*   tgt    = (const int*)d_in[1];
    unsigned long long* wsll = (unsigned long long*)d_ws;        // 10 x u64
    unsigned*           wsu  = (unsigned*)((char*)d_ws + 80);    // 10 x u32
    hipMemsetAsync(d_ws, 0, 120, stream);
    ghmc_main<<<kBlocks, kThreads, 0, stream>>>(logits, wsll, wsu);
    ghmc_fix<<<kB / 256, 256, 0, stream>>>(logits, tgt, wsll, wsu);
    ghmc_final<<<1, 64, 0, stream>>>(wsll, wsu, (float*)d_out);
}

// Round 8
// 37.230 us; speedup vs baseline: 1.5375x; 1.5375x over previous
//
#include <hip/hip_runtime.h>

typedef float v2f __attribute__((ext_vector_type(2)));

namespace {
constexpr int kB = 16384;
constexpr int kC = 1000;
constexpr int kNElem = kB * kC;           // 16,384,000
constexpr int kNV8 = kNElem / 8;          // 2,048,000 (8-float chunks)
constexpr int kV8PerRow = kC / 8;         // 125
constexpr int kBlocks = 1280;             // <=7 iters -> <=56 elems/thread (6-bit fields safe)
constexpr int kThreads = 256;
constexpr int kStride = kBlocks * kThreads;  // 327,680
}

// ws: float pf[10][kBlocks]  — per-block hinge-sum partials acc_j (c_0 = 0 -> T)
//     u32   pu[10][kBlocks]  — per-block bin-count partials N_k
// NO global atomics anywhere (R1-R7 were serialized on ~20K same-line atomic RMWs).
// finalize (f64): cnt_j = sum_{k>=j} N_k; cum_j = acc_j - c_j*(N - cnt_j);
//                 S_k = cum_k - cum_{k+1}; loss = (1/n) sum_{N_k>0} S_k/N_k.

__device__ __forceinline__ void ghmc_elem(float L, float& bce, unsigned& bin)
{
    const float kLn2   = 0.6931471805599453f;
    const float kNRLn2 = -1.4426950408889634f;
    const float en  = __builtin_amdgcn_exp2f(kNRLn2 * fabsf(L));  // e^{-|L|}
    const float den = 1.f + en;
    const float lg  = __builtin_amdgcn_logf(den);                 // log2(den)
    const float r   = __builtin_amdgcn_rcpf(den);
    bce = fmaf(lg, kLn2, fmaxf(L, 0.f));                          // softplus(L)
    unsigned babs = (unsigned)(10.f * r);
    babs = babs > 9u ? 9u : babs;                                 // in [5,9]
    bin = (L >= 0.f) ? babs : 9u - babs;
}

__device__ __forceinline__ void proc4(const float4 v,
    v2f& a01, v2f& a23, v2f& a45, v2f& a67, v2f& a89,
    unsigned long long& hcnt,
    const v2f C01, const v2f C23, const v2f C45, const v2f C67, const v2f C89)
{
    const float lv[4] = {v.x, v.y, v.z, v.w};
    #pragma unroll
    for (int e = 0; e < 4; ++e) {
        float bce; unsigned bin;
        ghmc_elem(lv[e], bce, bin);
        hcnt += 1ull << (6u * bin);
        const v2f b2 = {bce, bce};
        a01 += __builtin_elementwise_max(b2, C01);
        a23 += __builtin_elementwise_max(b2, C23);
        a45 += __builtin_elementwise_max(b2, C45);
        a67 += __builtin_elementwise_max(b2, C67);
        a89 += __builtin_elementwise_max(b2, C89);
    }
}

__global__ __launch_bounds__(kThreads) void ghmc_main(
    const float* __restrict__ logits,
    const int* __restrict__ tgt,
    float* __restrict__ pf,
    unsigned* __restrict__ pu)
{
    const v2f C01 = {0.0f,        0.10536052f};
    const v2f C23 = {0.22314355f, 0.35667494f};
    const v2f C45 = {0.51082562f, 0.69314718f};
    const v2f C67 = {0.91629073f, 1.20397280f};
    const v2f C89 = {1.60943791f, 2.30258509f};

    v2f a01 = {0.f,0.f}, a23 = {0.f,0.f}, a45 = {0.f,0.f},
        a67 = {0.f,0.f}, a89 = {0.f,0.f};
    unsigned long long hcnt = 0ull;

    const int gid = blockIdx.x * blockDim.x + threadIdx.x;
    const int n = (kNV8 - 1 - gid) / kStride + 1;   // 6 or 7 iterations
    const float4* __restrict__ Lp = reinterpret_cast<const float4*>(logits);

    // depth-2 software pipeline, clamped prefetch addresses (over-load harmless)
    int i = gid;
    int ib = i + kStride;     if (ib >= kNV8) ib = kNV8 - 1;
    float4 a0 = Lp[2 * i],  a1 = Lp[2 * i + 1];
    float4 b0 = Lp[2 * ib], b1 = Lp[2 * ib + 1];

    for (int k = 0; k < n; ++k) {
        int ic = i + 2 * kStride; if (ic >= kNV8) ic = kNV8 - 1;
        const float4 c0 = Lp[2 * ic], c1 = Lp[2 * ic + 1];

        // target lookup for the CURRENT chunk i (latency covered by the proc4s)
        const int row = i / kV8PerRow;                         // magic-mul div
        const int dt  = tgt[row] - (i - row * kV8PerRow) * 8;

        proc4(a0, a01, a23, a45, a67, a89, hcnt, C01, C23, C45, C67, C89);
        proc4(a1, a01, a23, a45, a67, a89, hcnt, C01, C23, C45, C67, C89);

        // rare correction: this 8-chunk holds the row's target element
        // (~26% of wave-iterations, 1-2 active lanes)
        if (__builtin_expect((unsigned)dt < 8u, 0)) {
            float L = a0.x;
            L = (dt == 1) ? a0.y : L;
            L = (dt == 2) ? a0.z : L;
            L = (dt == 3) ? a0.w : L;
            L = (dt == 4) ? a1.x : L;
            L = (dt == 5) ? a1.y : L;
            L = (dt == 6) ? a1.z : L;
            L = (dt == 7) ? a1.w : L;
            float bn_; unsigned bnb;
            ghmc_elem(L, bn_, bnb);            // what the main path added
            const float bt_ = bn_ - L;         // softplus(-L) = softplus(L) - L
            unsigned babs = (bnb >= 5u) ? bnb : 9u - bnb;   // |L|-bin in [5,9]
            const unsigned btb = (L <= 0.f) ? babs : 9u - babs;
            hcnt += (1ull << (6u * btb)) - (1ull << (6u * bnb));
            const v2f bn2 = {bn_, bn_}, bt2 = {bt_, bt_};
            a01 += __builtin_elementwise_max(bt2, C01) - __builtin_elementwise_max(bn2, C01);
            a23 += __builtin_elementwise_max(bt2, C23) - __builtin_elementwise_max(bn2, C23);
            a45 += __builtin_elementwise_max(bt2, C45) - __builtin_elementwise_max(bn2, C45);
            a67 += __builtin_elementwise_max(bt2, C67) - __builtin_elementwise_max(bn2, C67);
            a89 += __builtin_elementwise_max(bt2, C89) - __builtin_elementwise_max(bn2, C89);
        }

        a0 = b0; a1 = b1; b0 = c0; b1 = c1;
        i += kStride;
    }

    // expand 6-bit fields -> two u64 with 12-bit fields (wave sum <= 56*64 = 3584 < 4096)
    unsigned long long lo = 0ull, hi = 0ull;
    #pragma unroll
    for (int k = 0; k < 5; ++k) {
        lo += ((hcnt >> (6 * k))       & 63ull) << (12 * k);
        hi += ((hcnt >> (6 * (k + 5))) & 63ull) << (12 * k);
    }
    float r10[10] = {a01.x, a01.y, a23.x, a23.y, a45.x, a45.y, a67.x, a67.y, a89.x, a89.y};
    #pragma unroll
    for (int off = 32; off > 0; off >>= 1) {
        #pragma unroll
        for (int k = 0; k < 10; ++k) r10[k] += __shfl_down(r10[k], off);
        lo += __shfl_down(lo, off);
        hi += __shfl_down(hi, off);
    }

    __shared__ float              sf[4][10];
    __shared__ unsigned long long sc[4][2];
    const int wave = threadIdx.x >> 6;
    const int lane = threadIdx.x & 63;
    if (lane == 0) {
        #pragma unroll
        for (int k = 0; k < 10; ++k) sf[wave][k] = r10[k];
        sc[wave][0] = lo; sc[wave][1] = hi;
    }
    __syncthreads();
    // per-block partials: PLAIN STORES to a private row — zero global atomics
    const int t = threadIdx.x;
    if (t < 10) {
        pf[t * kBlocks + blockIdx.x] = sf[0][t] + sf[1][t] + sf[2][t] + sf[3][t];
    } else if (t < 20) {
        const int b = t - 10;
        const int half = (b < 5) ? 0 : 1;
        const int sh = 12 * (b < 5 ? b : b - 5);
        unsigned s = 0;
        #pragma unroll
        for (int w = 0; w < 4; ++w) s += (unsigned)((sc[w][half] >> sh) & 4095ull);
        pu[b * kBlocks + blockIdx.x] = s;
    }
}

// 10 waves: wave w reduces sum-slot w (f64) and count-slot w (u32), then finalize.
__global__ __launch_bounds__(640) void ghmc_reduce(
    const float* __restrict__ pf,
    const unsigned* __restrict__ pu,
    float* __restrict__ out)
{
    const int wave = threadIdx.x >> 6;
    const int lane = threadIdx.x & 63;

    double   fs = 0.0;
    unsigned cs = 0u;
    for (int b = lane; b < kBlocks; b += 64) {      // coalesced column reads
        fs += (double)pf[wave * kBlocks + b];
        cs += pu[wave * kBlocks + b];
    }
    #pragma unroll
    for (int off = 32; off > 0; off >>= 1) {
        fs += __shfl_down(fs, off);
        cs += __shfl_down(cs, off);
    }

    __shared__ double   sF[10];
    __shared__ unsigned sC[10];
    if (lane == 0) { sF[wave] = fs; sC[wave] = cs; }
    __syncthreads();

    if (threadIdx.x == 0) {
        const double cj[10] = {0.0,
            0.10536051565782630, 0.22314355131420976, 0.35667494393873245,
            0.51082562376599072, 0.69314718055994531, 0.91629073187415511,
            1.20397280432593600, 1.60943791243410040, 2.30258509299404570};
        double N[10], cnt[11], cum[11];
        for (int k = 0; k < 10; ++k) N[k] = (double)sC[k];
        cnt[10] = 0.0;
        for (int j = 9; j >= 0; --j) cnt[j] = cnt[j + 1] + N[j];
        cum[10] = 0.0;
        cum[0] = sF[0];                                   // T (c=0 hinge is exact)
        for (int j = 1; j <= 9; ++j)
            cum[j] = sF[j] - cj[j] * ((double)kNElem - cnt[j]);
        double loss = 0.0, n = 0.0;
        for (int k = 0; k < 10; ++k) {
            if (N[k] > 0.0) { n += 1.0; loss += (cum[k] - cum[k + 1]) / N[k]; }
        }
        out[0] = (float)(loss / (n > 1.0 ? n : 1.0));
    }
}

extern "C" void kernel_launch(void* const* d_in, const int* in_sizes, int n_in,
                              void* d_out, int out_size, void* d_ws, size_t ws_size,
                              hipStream_t stream)
{
    const float* logits = (const float*)d_in[0];
    const int*   tgt    = (const int*)d_in[1];
    float*    pf = (float*)d_ws;                                   // 10 x 1280 f32
    unsigned* pu = (unsigned*)((char*)d_ws + 10 * kBlocks * 4);    // 10 x 1280 u32
    ghmc_main<<<kBlocks, kThreads, 0, stream>>>(logits, tgt, pf, pu);
    ghmc_reduce<<<1, 640, 0, stream>>>(pf, pu, (float*)d_out);
}